// Round 10
// baseline (977.760 us; speedup 1.0000x reference)
//
#include <hip/hip_runtime.h>
#include <math.h>

#define NBP   10000
#define NPTS2 20000
#define NBATCH 2
#define KNN   16
#define QT    16
#define PH    16
#define TILE  1250
#define NTHREADS 256
#define COLL  32

// ---- grid constants ----
#define NC    36
#define NC3   (NC*NC*NC)          // 46656
#define NCELLS (2*NC3)            // 93312
#define BLO   (-64.0f)
#define CSZ   (128.0f/NC)
#define CINV  (NC/128.0f)
#define WS_COUNTS 0
#define WS_PK4    373248          // 93312*4, 16-aligned
#define WS_PIDX   693248          // +20000*16
#define WS_NEED   773248          // +20000*4

__device__ __forceinline__ int cell_xyz(float v) {
    int c = (int)((v - BLO) * CINV);
    return min(NC - 1, max(0, c));
}
__device__ __forceinline__ int cell_of(float x, float y, float z) {
    return (cell_xyz(z) * NC + cell_xyz(y)) * NC + cell_xyz(x);
}

// ---------------- grid build kernels (r9-verbatim) ----------------
__global__ __launch_bounds__(NTHREADS)
void k_zero(int* __restrict__ counts) {
    int i = blockIdx.x * NTHREADS + threadIdx.x;
    if (i < NCELLS) counts[i] = 0;
}

__global__ __launch_bounds__(NTHREADS)
void k_hist(const float* __restrict__ coord, int* __restrict__ counts) {
    int i = blockIdx.x * NTHREADS + threadIdx.x;
    if (i < NPTS2) {
        float x = coord[3*i], y = coord[3*i+1], z = coord[3*i+2];
        int g = (i / NBP) * NC3 + cell_of(x, y, z);
        atomicAdd(&counts[g], 1);
    }
}

#define PCH 92   // 1024*92 >= 93312
__global__ __launch_bounds__(1024)
void k_prefix(int* __restrict__ counts) {
    __shared__ int part[1024];
    int t = threadIdx.x;
    int base = t * PCH;
    int s = 0;
    for (int i = 0; i < PCH; ++i) { int idx = base + i; if (idx < NCELLS) s += counts[idx]; }
    part[t] = s;
    __syncthreads();
    if (t == 0) { int run = 0; for (int j = 0; j < 1024; ++j) { int tmp = part[j]; part[j] = run; run += tmp; } }
    __syncthreads();
    int run = part[t];
    for (int i = 0; i < PCH; ++i) {
        int idx = base + i;
        if (idx < NCELLS) { int tmp = counts[idx]; counts[idx] = run; run += tmp; }
    }
}

__global__ __launch_bounds__(NTHREADS)
void k_scatter(const float* __restrict__ coord, int* __restrict__ counts,
               float4* __restrict__ pk4, int* __restrict__ pidx) {
    int i = blockIdx.x * NTHREADS + threadIdx.x;
    if (i < NPTS2) {
        float x = coord[3*i], y = coord[3*i+1], z = coord[3*i+2];
        int g = (i / NBP) * NC3 + cell_of(x, y, z);
        int slot = atomicAdd(&counts[g], 1);
        float sq = __fadd_rn(__fadd_rn(__fmul_rn(x,x), __fmul_rn(y,y)), __fmul_rn(z,z));
        pk4[slot] = make_float4(x, y, z, sq);
        pidx[slot] = i - (i / NBP) * NBP;   // local index within batch
    }
}

// ---------------- main kernel: r8 pass-1/merge/tail + grid-ball pass-2 ----------------
__global__ __launch_bounds__(NTHREADS)
void pfas_gridc(const float* __restrict__ feat, const float* __restrict__ coord,
                const int* __restrict__ counts, const float4* __restrict__ pk4,
                const int* __restrict__ pidx,
                const float* __restrict__ W1, const float* __restrict__ b1,
                const float* __restrict__ gmm, const float* __restrict__ bta,
                const float* __restrict__ rmean, const float* __restrict__ rvar,
                const float* __restrict__ W2, const float* __restrict__ b2,
                float* __restrict__ out)
{
    __shared__ float4 s_cand[TILE];          // 20000 B; aliased for pass-1 value lists
    __shared__ float  s_tau[QT];
    __shared__ float2 s_coll[QT][COLL];      // 4096 B
    __shared__ int    s_cnt[QT];

    const int tid = threadIdx.x;
    const int ql  = tid >> 4;
    const int ph  = tid & 15;
    const int bb  = blockIdx.y;
    const int qi  = blockIdx.x * QT + ql;
    const int gbase = bb * NBP;
    const int gq  = gbase + qi;

    const float qx = coord[3*gq], qy = coord[3*gq+1], qz = coord[3*gq+2];
    const float qsq = __fadd_rn(__fadd_rn(__fmul_rn(qx,qx), __fmul_rn(qy,qy)), __fmul_rn(qz,qz));

    if (tid < QT) s_cnt[tid] = 0;

    // ---------------- pass 1: branchless value-only top-16 (r8-verbatim) ----------------
    float td[KNN];
    #pragma unroll
    for (int s = 0; s < KNN; ++s) td[s] = INFINITY;

    for (int t0 = 0; t0 < NBP; t0 += TILE) {
        __syncthreads();
        for (int c = tid; c < TILE; c += NTHREADS) {
            const float* cp = coord + (size_t)(gbase + t0 + c) * 3;
            float x = cp[0], y = cp[1], z = cp[2];
            float sq = __fadd_rn(__fadd_rn(__fmul_rn(x,x), __fmul_rn(y,y)), __fmul_rn(z,z));
            s_cand[c] = make_float4(x, y, z, sq);
        }
        __syncthreads();
        for (int k = ph; k < TILE; k += PH) {
            const float4 c = s_cand[k];
            float dot = __fadd_rn(__fadd_rn(__fmul_rn(qx,c.x), __fmul_rn(qy,c.y)), __fmul_rn(qz,c.z));
            float d2  = __fsub_rn(__fadd_rn(qsq, c.w), __fmul_rn(2.0f, dot));
            float v = (t0 + k == qi) ? INFINITY : d2;
            #pragma unroll
            for (int s = 0; s < KNN; ++s) { float t = td[s]; td[s] = fminf(t, v); v = fmaxf(t, v); }
        }
    }

    __syncthreads();
    float* lists = reinterpret_cast<float*>(s_cand);    // 16*256*4 = 16384 B <= 20000 B
    #pragma unroll
    for (int s = 0; s < KNN; ++s) lists[s*NTHREADS + tid] = td[s];
    __syncthreads();

    // one lane per query: 16-way merge -> tau = exact 16th smallest (r8-verbatim)
    if (tid < QT) {
        const int lane0 = tid * PH;
        int h0=0,h1=0,h2=0,h3=0,h4=0,h5=0,h6=0,h7=0,h8=0,h9=0,h10=0,h11=0,h12=0,h13=0,h14=0,h15=0;
        float tau = INFINITY;
        #pragma unroll
        for (int o = 0; o < KNN; ++o) {
            float best = INFINITY; int sel = 0;
            #define CHK(P, H) { float e = ((H) < KNN) ? lists[(H)*NTHREADS + lane0 + (P)] : INFINITY; \
                                if (e < best) { best = e; sel = (P); } }
            CHK(0,h0)  CHK(1,h1)  CHK(2,h2)  CHK(3,h3)
            CHK(4,h4)  CHK(5,h5)  CHK(6,h6)  CHK(7,h7)
            CHK(8,h8)  CHK(9,h9)  CHK(10,h10) CHK(11,h11)
            CHK(12,h12) CHK(13,h13) CHK(14,h14) CHK(15,h15)
            #undef CHK
            tau = best;
            h0 += (sel==0);  h1 += (sel==1);  h2 += (sel==2);  h3 += (sel==3);
            h4 += (sel==4);  h5 += (sel==5);  h6 += (sel==6);  h7 += (sel==7);
            h8 += (sel==8);  h9 += (sel==9);  h10+= (sel==10); h11+= (sel==11);
            h12+= (sel==12); h13+= (sel==13); h14+= (sel==14); h15+= (sel==15);
        }
        s_tau[tid] = tau;
    }
    __syncthreads();

    // ---------------- pass 2: grid-ball collect of (d2, idx) with d2 <= tau ----------------
    // Any point with computed d2 <= tau has true distance <= sqrt(tau + 2e-3) < rr.
    // cell_xyz is monotone, so scanning cell ranges of [q-rr, q+rr] covers the ball
    // (domain-clamped points land in boundary cells inside the range). pk4.w is computed
    // with the identical rounding sequence as pass-1, so d2 bits match pass-1 exactly.
    {
        const float tau = s_tau[ql];
        const float rr = __fadd_rn(__fmul_rn(sqrtf(fmaxf(tau, 0.f)), 1.001f), 0.01f);
        const int cx0 = cell_xyz(qx - rr), cx1 = cell_xyz(qx + rr);
        const int cy0 = cell_xyz(qy - rr), cy1 = cell_xyz(qy + rr);
        const int cz0 = cell_xyz(qz - rr), cz1 = cell_xyz(qz + rr);
        for (int az = cz0; az <= cz1; ++az) {
            for (int ay = cy0; ay <= cy1; ++ay) {
                for (int ax = cx0; ax <= cx1; ++ax) {
                    int g  = bb * NC3 + (az * NC + ay) * NC + ax;
                    int st = (g == 0) ? 0 : counts[g-1];
                    int en = counts[g];
                    st = max(0, min(st, NPTS2)); en = max(st, min(en, NPTS2));
                    for (int i = st + ph; i < en; i += PH) {
                        float4 c = pk4[i];
                        float dot = __fadd_rn(__fadd_rn(__fmul_rn(qx,c.x), __fmul_rn(qy,c.y)), __fmul_rn(qz,c.z));
                        float d2  = __fsub_rn(__fadd_rn(qsq, c.w), __fmul_rn(2.0f, dot));
                        int j = pidx[i];
                        if (d2 <= tau && j != qi) {
                            int slot = atomicAdd(&s_cnt[ql], 1);
                            if (slot < COLL) s_coll[ql][slot] = make_float2(d2, __int_as_float(j));
                        }
                    }
                }
            }
        }
    }
    __syncthreads();

    // ---------------- tail: per-query select-16, PCA, MLP, blend (r8-verbatim) ----------------
    if (tid < QT) {
        const int q  = tid;
        const int qq = blockIdx.x * QT + q;
        const int gq2 = gbase + qq;
        const int n  = min(s_cnt[q], COLL);

        int bi[KNN];
        float sumd = 0.f;
        #pragma unroll
        for (int o = 0; o < KNN; ++o) {
            float best = INFINITY; int besti = qq; int sl = -1;
            for (int e = 0; e < n; ++e) {
                float2 en = s_coll[q][e];
                int ix = __float_as_int(en.y);
                if (en.x < best || (en.x == best && ix < besti)) { best = en.x; besti = ix; sl = e; }
            }
            if (sl >= 0) s_coll[q][sl].x = INFINITY;
            bi[o] = besti;
            sumd = __fadd_rn(sumd, sqrtf(fmaxf(best, 0.f)));
        }
        const float mean_dist = sumd * (1.0f / KNN);
        const float density   = 1.0f / (mean_dist + 1e-6f);

        float mx = 0.f, my = 0.f, mz = 0.f;
        #pragma unroll
        for (int o = 0; o < KNN; ++o) {
            const float* cp = coord + (size_t)(gbase + bi[o]) * 3;
            mx += cp[0]; my += cp[1]; mz += cp[2];
        }
        mx *= (1.0f/KNN); my *= (1.0f/KNN); mz *= (1.0f/KNN);
        double cxx=0, cxy=0, cxz=0, cyy=0, cyz=0, czz=0;
        #pragma unroll
        for (int o = 0; o < KNN; ++o) {
            const float* cp = coord + (size_t)(gbase + bi[o]) * 3;
            double dx = (double)cp[0] - (double)mx;
            double dy = (double)cp[1] - (double)my;
            double dz = (double)cp[2] - (double)mz;
            cxx += dx*dx; cxy += dx*dy; cxz += dx*dz;
            cyy += dy*dy; cyz += dy*dz; czz += dz*dz;
        }
        const double inv = 1.0 / (KNN - 1);
        cxx *= inv; cxy *= inv; cxz *= inv; cyy *= inv; cyz *= inv; czz *= inv;

        double qm = (cxx + cyy + czz) / 3.0;
        double p1 = cxy*cxy + cxz*cxz + cyz*cyz;
        double b00 = cxx - qm, b11 = cyy - qm, b22 = czz - qm;
        double p2 = b00*b00 + b11*b11 + b22*b22 + 2.0*p1;
        double pp = sqrt(p2 / 6.0);
        double e0, e1, e2;
        if (pp < 1e-30) { e0 = e1 = e2 = qm; }
        else {
            double ip = 1.0 / pp;
            double c00 = b00*ip, c11 = b11*ip, c22 = b22*ip;
            double c01 = cxy*ip, c02 = cxz*ip, c12 = cyz*ip;
            double detB = c00*(c11*c22 - c12*c12)
                        - c01*(c01*c22 - c12*c02)
                        + c02*(c01*c12 - c11*c02);
            double r = detB * 0.5;
            r = fmin(1.0, fmax(-1.0, r));
            double phi = acos(r) / 3.0;
            e0 = qm + 2.0*pp*cos(phi);
            e2 = qm + 2.0*pp*cos(phi + 2.0943951023931953);
            e1 = 3.0*qm - e0 - e2;
        }
        const float lin = (float)((e0 - e1 - e2) / (e0 + e1 + e2 + 1e-6));

        const float* fr = feat + (size_t)gq2 * 64;
        float h[32];
        #pragma unroll
        for (int j = 0; j < 32; ++j) h[j] = b1[j];
        for (int i = 0; i < 64; ++i) {
            float fi = fr[i];
            #pragma unroll
            for (int j = 0; j < 32; ++j) h[j] = fmaf(fi, W1[i*32 + j], h[j]);
        }
        float l0 = b2[0], l1 = b2[1], l2 = b2[2];
        #pragma unroll
        for (int j = 0; j < 32; ++j) {
            float invstd = 1.0f / sqrtf(rvar[j] + 1e-5f);
            float hb = (h[j] - rmean[j]) * invstd * gmm[j] + bta[j];
            hb = fmaxf(hb, 0.f);
            l0 = fmaf(hb, W2[j*3+0], l0);
            l1 = fmaf(hb, W2[j*3+1], l1);
            l2 = fmaf(hb, W2[j*3+2], l2);
        }
        float m  = fmaxf(l0, fmaxf(l1, l2));
        float x0 = expf(l0 - m), x1 = expf(l1 - m), x2 = expf(l2 - m);
        float es = x0 + x1 + x2;
        float p0 = x0/es, pb = x1/es, pl = x2/es;

        float tower = (density*2.0f + p0) / 3.0f;
        float back  = (fmaxf(1.0f - lin, 1.0f - density) + pb) / 3.0f;
        float line  = (lin*2.0f + pl) / 3.0f;
        float g01 = tower*0.1f + back*1.0f + line*0.3f + 1e-6f;
        float g2  = tower*0.1f + back*1.0f + line*1.5f + 1e-6f;
        out[(size_t)gq2*3 + 0] = g01;
        out[(size_t)gq2*3 + 1] = g01;
        out[(size_t)gq2*3 + 2] = g2;
    }
}

// ---------------- r8 fallback kernel (verbatim, used when ws too small) ----------------
__global__ __launch_bounds__(NTHREADS)
void pfas_kernel(const float* __restrict__ feat, const float* __restrict__ coord,
                 const float* __restrict__ W1, const float* __restrict__ b1,
                 const float* __restrict__ gmm, const float* __restrict__ bta,
                 const float* __restrict__ rmean, const float* __restrict__ rvar,
                 const float* __restrict__ W2, const float* __restrict__ b2,
                 float* __restrict__ out)
{
    __shared__ float4 s_cand[TILE];
    __shared__ float  s_tau[QT];
    __shared__ float2 s_coll[QT][COLL];
    __shared__ int    s_cnt[QT];

    const int tid = threadIdx.x;
    const int ql  = tid >> 4;
    const int ph  = tid & 15;
    const int b   = blockIdx.y;
    const int qi  = blockIdx.x * QT + ql;
    const int gq  = b * NBP + qi;

    const float qx = coord[3*gq], qy = coord[3*gq+1], qz = coord[3*gq+2];
    const float qsq = __fadd_rn(__fadd_rn(__fmul_rn(qx,qx), __fmul_rn(qy,qy)), __fmul_rn(qz,qz));

    if (tid < QT) s_cnt[tid] = 0;

    float td[KNN];
    #pragma unroll
    for (int s = 0; s < KNN; ++s) td[s] = INFINITY;

    for (int t0 = 0; t0 < NBP; t0 += TILE) {
        __syncthreads();
        for (int c = tid; c < TILE; c += NTHREADS) {
            const float* cp = coord + (size_t)(b*NBP + t0 + c) * 3;
            float x = cp[0], y = cp[1], z = cp[2];
            float sq = __fadd_rn(__fadd_rn(__fmul_rn(x,x), __fmul_rn(y,y)), __fmul_rn(z,z));
            s_cand[c] = make_float4(x, y, z, sq);
        }
        __syncthreads();
        for (int k = ph; k < TILE; k += PH) {
            const float4 c = s_cand[k];
            float dot = __fadd_rn(__fadd_rn(__fmul_rn(qx,c.x), __fmul_rn(qy,c.y)), __fmul_rn(qz,c.z));
            float d2  = __fsub_rn(__fadd_rn(qsq, c.w), __fmul_rn(2.0f, dot));
            float v = (t0 + k == qi) ? INFINITY : d2;
            #pragma unroll
            for (int s = 0; s < KNN; ++s) { float t = td[s]; td[s] = fminf(t, v); v = fmaxf(t, v); }
        }
    }
    __syncthreads();
    float* lists = reinterpret_cast<float*>(s_cand);
    #pragma unroll
    for (int s = 0; s < KNN; ++s) lists[s*NTHREADS + tid] = td[s];
    __syncthreads();
    if (tid < QT) {
        const int lane0 = tid * PH;
        int h0=0,h1=0,h2=0,h3=0,h4=0,h5=0,h6=0,h7=0,h8=0,h9=0,h10=0,h11=0,h12=0,h13=0,h14=0,h15=0;
        float tau = INFINITY;
        #pragma unroll
        for (int o = 0; o < KNN; ++o) {
            float best = INFINITY; int sel = 0;
            #define CHK(P, H) { float e = ((H) < KNN) ? lists[(H)*NTHREADS + lane0 + (P)] : INFINITY; \
                                if (e < best) { best = e; sel = (P); } }
            CHK(0,h0)  CHK(1,h1)  CHK(2,h2)  CHK(3,h3)
            CHK(4,h4)  CHK(5,h5)  CHK(6,h6)  CHK(7,h7)
            CHK(8,h8)  CHK(9,h9)  CHK(10,h10) CHK(11,h11)
            CHK(12,h12) CHK(13,h13) CHK(14,h14) CHK(15,h15)
            #undef CHK
            tau = best;
            h0 += (sel==0);  h1 += (sel==1);  h2 += (sel==2);  h3 += (sel==3);
            h4 += (sel==4);  h5 += (sel==5);  h6 += (sel==6);  h7 += (sel==7);
            h8 += (sel==8);  h9 += (sel==9);  h10+= (sel==10); h11+= (sel==11);
            h12+= (sel==12); h13+= (sel==13); h14+= (sel==14); h15+= (sel==15);
        }
        s_tau[tid] = tau;
    }
    __syncthreads();
    const float tau = s_tau[ql];
    for (int t0 = 0; t0 < NBP; t0 += TILE) {
        __syncthreads();
        for (int c = tid; c < TILE; c += NTHREADS) {
            const float* cp = coord + (size_t)(b*NBP + t0 + c) * 3;
            float x = cp[0], y = cp[1], z = cp[2];
            float sq = __fadd_rn(__fadd_rn(__fmul_rn(x,x), __fmul_rn(y,y)), __fmul_rn(z,z));
            s_cand[c] = make_float4(x, y, z, sq);
        }
        __syncthreads();
        for (int k = ph; k < TILE; k += PH) {
            const float4 c = s_cand[k];
            float dot = __fadd_rn(__fadd_rn(__fmul_rn(qx,c.x), __fmul_rn(qy,c.y)), __fmul_rn(qz,c.z));
            float d2  = __fsub_rn(__fadd_rn(qsq, c.w), __fmul_rn(2.0f, dot));
            int j = t0 + k;
            if (d2 <= tau && j != qi) {
                int slot = atomicAdd(&s_cnt[ql], 1);
                if (slot < COLL) s_coll[ql][slot] = make_float2(d2, __int_as_float(j));
            }
        }
    }
    __syncthreads();
    if (tid < QT) {
        const int q  = tid;
        const int qq = blockIdx.x * QT + q;
        const int gq2 = b * NBP + qq;
        const int n  = min(s_cnt[q], COLL);
        int bi[KNN];
        float sumd = 0.f;
        #pragma unroll
        for (int o = 0; o < KNN; ++o) {
            float best = INFINITY; int besti = qq; int sl = -1;
            for (int e = 0; e < n; ++e) {
                float2 en = s_coll[q][e];
                int ix = __float_as_int(en.y);
                if (en.x < best || (en.x == best && ix < besti)) { best = en.x; besti = ix; sl = e; }
            }
            if (sl >= 0) s_coll[q][sl].x = INFINITY;
            bi[o] = besti;
            sumd = __fadd_rn(sumd, sqrtf(fmaxf(best, 0.f)));
        }
        const float mean_dist = sumd * (1.0f / KNN);
        const float density   = 1.0f / (mean_dist + 1e-6f);
        float mx = 0.f, my = 0.f, mz = 0.f;
        #pragma unroll
        for (int o = 0; o < KNN; ++o) {
            const float* cp = coord + (size_t)(b*NBP + bi[o]) * 3;
            mx += cp[0]; my += cp[1]; mz += cp[2];
        }
        mx *= (1.0f/KNN); my *= (1.0f/KNN); mz *= (1.0f/KNN);
        double cxx=0, cxy=0, cxz=0, cyy=0, cyz=0, czz=0;
        #pragma unroll
        for (int o = 0; o < KNN; ++o) {
            const float* cp = coord + (size_t)(b*NBP + bi[o]) * 3;
            double dx = (double)cp[0] - (double)mx;
            double dy = (double)cp[1] - (double)my;
            double dz = (double)cp[2] - (double)mz;
            cxx += dx*dx; cxy += dx*dy; cxz += dx*dz;
            cyy += dy*dy; cyz += dy*dz; czz += dz*dz;
        }
        const double inv = 1.0 / (KNN - 1);
        cxx *= inv; cxy *= inv; cxz *= inv; cyy *= inv; cyz *= inv; czz *= inv;
        double qm = (cxx + cyy + czz) / 3.0;
        double p1 = cxy*cxy + cxz*cxz + cyz*cyz;
        double b00 = cxx - qm, b11 = cyy - qm, b22 = czz - qm;
        double p2 = b00*b00 + b11*b11 + b22*b22 + 2.0*p1;
        double pp = sqrt(p2 / 6.0);
        double e0, e1, e2;
        if (pp < 1e-30) { e0 = e1 = e2 = qm; }
        else {
            double ip = 1.0 / pp;
            double c00 = b00*ip, c11 = b11*ip, c22 = b22*ip;
            double c01 = cxy*ip, c02 = cxz*ip, c12 = cyz*ip;
            double detB = c00*(c11*c22 - c12*c12) - c01*(c01*c22 - c12*c02) + c02*(c01*c12 - c11*c02);
            double r = detB * 0.5;
            r = fmin(1.0, fmax(-1.0, r));
            double phi = acos(r) / 3.0;
            e0 = qm + 2.0*pp*cos(phi);
            e2 = qm + 2.0*pp*cos(phi + 2.0943951023931953);
            e1 = 3.0*qm - e0 - e2;
        }
        const float lin = (float)((e0 - e1 - e2) / (e0 + e1 + e2 + 1e-6));
        const float* fr = feat + (size_t)gq2 * 64;
        float h[32];
        #pragma unroll
        for (int j = 0; j < 32; ++j) h[j] = b1[j];
        for (int i = 0; i < 64; ++i) {
            float fi = fr[i];
            #pragma unroll
            for (int j = 0; j < 32; ++j) h[j] = fmaf(fi, W1[i*32 + j], h[j]);
        }
        float l0 = b2[0], l1 = b2[1], l2 = b2[2];
        #pragma unroll
        for (int j = 0; j < 32; ++j) {
            float invstd = 1.0f / sqrtf(rvar[j] + 1e-5f);
            float hb = (h[j] - rmean[j]) * invstd * gmm[j] + bta[j];
            hb = fmaxf(hb, 0.f);
            l0 = fmaf(hb, W2[j*3+0], l0);
            l1 = fmaf(hb, W2[j*3+1], l1);
            l2 = fmaf(hb, W2[j*3+2], l2);
        }
        float m  = fmaxf(l0, fmaxf(l1, l2));
        float x0 = expf(l0 - m), x1 = expf(l1 - m), x2 = expf(l2 - m);
        float es = x0 + x1 + x2;
        float p0 = x0/es, pb = x1/es, pl = x2/es;
        float tower = (density*2.0f + p0) / 3.0f;
        float back  = (fmaxf(1.0f - lin, 1.0f - density) + pb) / 3.0f;
        float line  = (lin*2.0f + pl) / 3.0f;
        float g01 = tower*0.1f + back*1.0f + line*0.3f + 1e-6f;
        float g2  = tower*0.1f + back*1.0f + line*1.5f + 1e-6f;
        out[(size_t)gq2*3 + 0] = g01;
        out[(size_t)gq2*3 + 1] = g01;
        out[(size_t)gq2*3 + 2] = g2;
    }
}

extern "C" void kernel_launch(void* const* d_in, const int* in_sizes, int n_in,
                              void* d_out, int out_size, void* d_ws, size_t ws_size,
                              hipStream_t stream) {
    const float* feat  = (const float*)d_in[0];
    const float* coord = (const float*)d_in[1];
    const float* W1    = (const float*)d_in[3];
    const float* b1    = (const float*)d_in[4];
    const float* gmm   = (const float*)d_in[5];
    const float* bta   = (const float*)d_in[6];
    const float* rmean = (const float*)d_in[7];
    const float* rvar  = (const float*)d_in[8];
    const float* W2    = (const float*)d_in[9];
    const float* b2    = (const float*)d_in[10];
    float* out = (float*)d_out;

    dim3 grid(NBP / QT, NBATCH);   // 625 x 2

    if (ws_size >= (size_t)WS_NEED) {
        int*    counts = (int*)((char*)d_ws + WS_COUNTS);
        float4* pk4    = (float4*)((char*)d_ws + WS_PK4);
        int*    pidx   = (int*)((char*)d_ws + WS_PIDX);
        k_zero   <<<(NCELLS + NTHREADS-1)/NTHREADS, NTHREADS, 0, stream>>>(counts);
        k_hist   <<<(NPTS2  + NTHREADS-1)/NTHREADS, NTHREADS, 0, stream>>>(coord, counts);
        k_prefix <<<1, 1024, 0, stream>>>(counts);
        k_scatter<<<(NPTS2  + NTHREADS-1)/NTHREADS, NTHREADS, 0, stream>>>(coord, counts, pk4, pidx);
        pfas_gridc<<<grid, NTHREADS, 0, stream>>>(feat, coord, counts, pk4, pidx,
                                                  W1, b1, gmm, bta, rmean, rvar, W2, b2, out);
    } else {
        pfas_kernel<<<grid, NTHREADS, 0, stream>>>(feat, coord, W1, b1, gmm, bta,
                                                   rmean, rvar, W2, b2, out);
    }
}